// Round 1
// baseline (404.156 us; speedup 1.0000x reference)
//
#include <hip/hip_runtime.h>
#include <hip/hip_bf16.h>
#include <stdint.h>

#define NROWS 131072
#define EPSBN 1e-5f
#define LEAKK 0.33f

typedef __bf16 bf16x8_t __attribute__((ext_vector_type(8)));
typedef float  f32x4_t  __attribute__((ext_vector_type(4)));

__device__ __forceinline__ float leaky_f(float x) { return fmaxf(x, LEAKK * x); }

#define GLDS16(g, l)                                                          \
    __builtin_amdgcn_global_load_lds(                                         \
        (const __attribute__((address_space(1))) void*)(g),                   \
        (__attribute__((address_space(3))) void*)(l), 16, 0, 0)

#define CFENCE() asm volatile("" ::: "memory")

// Barrier-free gather-GEMM conv.
// out[n,d] = sum_k sum_c src[cidxT[k][n],c] * w[k,c,d]; cidxT premasked
// (masked-out -> row NROWS = zeros). Block: 256 rows, wave tile 64x64.
//
// Restructure vs r-prev (400us, ~40us/conv, latency/barrier-bound):
//  - ALL 9 B tiles (72KB) staged to LDS once up front via global_load_lds
//    with the XOR chunk swizzle (2-way conflicts = free on ds_read_b128).
//    One vmcnt(0) + one s_barrier for the whole kernel.
//  - A operand gathered DIRECTLY into MFMA A-fragment registers: lane
//    (quad,l15) of wave wv loads src[idx[row]]*128 + quad*16 + ks*64 with a
//    per-lane global_load_dwordx4 -- exactly the 16x16x32 A-frag layout.
//    No A slab, no LDS round-trip, and NO barriers in the k-loop: waves
//    free-run with idx prefetched 2 steps ahead and A double-buffered
//    1 step ahead (compiler emits counted vmcnt(12) waits).
__global__ __launch_bounds__(256, 2) void conv_kernel(
    const __bf16* __restrict__ src,      // (NROWS+1) x 64, row NROWS = zeros
    const int* __restrict__ cidxT,       // [9][NROWS]
    const __bf16* __restrict__ wt,       // [9][64 d][64 c]
    __bf16* __restrict__ dst,
    float* __restrict__ stat_out)
{
    __shared__ char Bw[9][8192];         // 72KB -> 2 blocks/CU

    const int tid  = threadIdx.x;
    const int lane = tid & 63;
    const int wv   = tid >> 6;
    const int quad = lane >> 4;
    const int l15  = lane & 15;
    const int row0 = blockIdx.x << 8;          // 256 rows/block
    const int srow = tid >> 3;                 // staging base row (0..31)
    const int cg   = (tid & 7) ^ (srow & 7);   // swizzled global chunk
    const int ldsl = (tid & 192) << 4;         // wave-uniform lds sub-base
    const int sxor = l15 & 7;

    const char* srcb = (const char*)src;
    const char* wtb  = (const char*)wt;

    f32x4_t acc[4][4];
#pragma unroll
    for (int mt = 0; mt < 4; ++mt)
#pragma unroll
        for (int nt = 0; nt < 4; ++nt)
            acc[mt][nt] = (f32x4_t){0.f, 0.f, 0.f, 0.f};

    const int ibase = row0 + (wv << 6) + l15;  // wave's row, + mt*16 per mt
    const unsigned qofs = (unsigned)(quad << 4);

    // idx prologue: k=0, k=1 (lanes 16-63 duplicate l15's value; broadcast)
    int ixv[2][4];
#pragma unroll
    for (int mt = 0; mt < 4; ++mt) ixv[0][mt] = cidxT[ibase + (mt << 4)];
#pragma unroll
    for (int mt = 0; mt < 4; ++mt) ixv[1][mt] = cidxT[NROWS + ibase + (mt << 4)];
    CFENCE();
    // stage ALL B tiles once: LDS[k][row][pos] holds global chunk pos^(row&7)
#pragma unroll
    for (int k = 0; k < 9; ++k)
#pragma unroll
        for (int i = 0; i < 2; ++i)
            GLDS16(wtb + (k << 13) + (((i << 5) + srow) << 7) + (cg << 4),
                   &Bw[k][(i << 12) + ldsl]);
    CFENCE();
    asm volatile("s_waitcnt vmcnt(0)" ::: "memory");  // B (and idx) retired
    __builtin_amdgcn_s_barrier();                     // B visible to all
    CFENCE();

    // A[0] into registers (idx already retired -> no wait)
    bf16x8_t areg[2][4][2];
#pragma unroll
    for (int mt = 0; mt < 4; ++mt) {
        unsigned vo = ((unsigned)ixv[0][mt] << 7) + qofs;
#pragma unroll
        for (int ks = 0; ks < 2; ++ks)
            areg[0][mt][ks] = *(const bf16x8_t*)(srcb + vo + (ks << 6));
    }
    CFENCE();

    // barrier-free k-loop. Queue per iter: [idx k+1][A k][idx k+2][A k+1]
    // -> consuming A[k] or idx[k+1] is vmcnt(12); up to 24 loads in flight.
#pragma unroll
    for (int k = 0; k < 9; ++k) {
        if (k < 7) {        // idx[k+2] into the slot freed by A[k]'s issue
#pragma unroll
            for (int mt = 0; mt < 4; ++mt)
                ixv[k & 1][mt] = cidxT[(k + 2) * NROWS + ibase + (mt << 4)];
        }
        if (k < 8) {        // issue A[k+1] gathers (waits idx[k+1] only)
#pragma unroll
            for (int mt = 0; mt < 4; ++mt) {
                unsigned vo = ((unsigned)ixv[(k + 1) & 1][mt] << 7) + qofs;
#pragma unroll
                for (int ks = 0; ks < 2; ++ks)
                    areg[(k + 1) & 1][mt][ks] =
                        *(const bf16x8_t*)(srcb + vo + (ks << 6));
            }
        }
        CFENCE();
        // B fragments from LDS (2-way conflict = free)
        bf16x8_t bq[4][2];
#pragma unroll
        for (int ks = 0; ks < 2; ++ks) {
            const int slot = ((quad | (ks << 2)) ^ sxor) << 4;
#pragma unroll
            for (int nt = 0; nt < 4; ++nt)
                bq[nt][ks] = *(const bf16x8_t*)
                    &Bw[k][(((nt << 4) + l15) << 7) + slot];
        }
#pragma unroll
        for (int ks = 0; ks < 2; ++ks)
#pragma unroll
            for (int mt = 0; mt < 4; ++mt)
#pragma unroll
                for (int nt = 0; nt < 4; ++nt)
                    acc[mt][nt] = __builtin_amdgcn_mfma_f32_16x16x32_bf16(
                        areg[k & 1][mt][ks], bq[nt][ks], acc[mt][nt], 0, 0, 0);
        CFENCE();
    }

    // store (D layout: row = quad*4+reg, col = lane&15)
#pragma unroll
    for (int mt = 0; mt < 4; ++mt) {
        int rowb = row0 + (wv << 6) + (mt << 4) + (quad << 2);
#pragma unroll
        for (int nt = 0; nt < 4; ++nt) {
            int col = (nt << 4) + l15;
#pragma unroll
            for (int r = 0; r < 4; ++r)
                dst[((size_t)(rowb + r) << 6) + col] = (__bf16)acc[mt][nt][r];
        }
    }
    // stats; red[] reuses Bw (all waves past their k-loops after this sync)
    float* red = (float*)Bw;
    __syncthreads();
    if (tid < 128) red[tid] = 0.f;
    __syncthreads();
#pragma unroll
    for (int nt = 0; nt < 4; ++nt) {
        float s = 0.f, q = 0.f;
#pragma unroll
        for (int mt = 0; mt < 4; ++mt)
#pragma unroll
            for (int r = 0; r < 4; ++r) { float v = acc[mt][nt][r]; s += v; q += v * v; }
        s += __shfl_xor(s, 16); s += __shfl_xor(s, 32);
        q += __shfl_xor(q, 16); q += __shfl_xor(q, 32);
        if (lane < 16) {
            atomicAdd(&red[(nt << 4) + lane], s);
            atomicAdd(&red[64 + (nt << 4) + lane], q);
        }
    }
    __syncthreads();
    if (tid < 128) atomicAdd(&stat_out[tid], red[tid]);
}

// in-place y = leaky(bn(y)) on bf16
__global__ __launch_bounds__(256) void bnact_kernel(
    __bf16* __restrict__ y, const float* __restrict__ stat,
    const float* __restrict__ gamma, const float* __restrict__ beta)
{
    __shared__ float sc[64], sh[64];
    int tid = threadIdx.x;
    if (tid < 64) {
        float m = stat[tid] * (1.f / NROWS);
        float v = stat[64 + tid] * (1.f / NROWS) - m * m;
        float s = gamma[tid] * rsqrtf(v + EPSBN);
        sc[tid] = s;
        sh[tid] = beta[tid] - m * s;
    }
    __syncthreads();
    size_t base = ((((size_t)blockIdx.x << 8) | tid) << 3);
    int c0 = (int)(base & 63);
    bf16x8_t hv = *(bf16x8_t*)(y + base);
#pragma unroll
    for (int j = 0; j < 8; ++j) {
        float f = (float)hv[j];
        f = leaky_f(f * sc[c0 + j] + sh[c0 + j]);
        hv[j] = (__bf16)f;
    }
    *(bf16x8_t*)(y + base) = hv;
}

// x_new = leaky(bn2(z) + x). Residual stream is bf16-only (xh). Block 0 reads
// feat (fp32); final block writes d_out (fp32) and skips the xh write.
__global__ __launch_bounds__(256) void resid_kernel(
    const __bf16* __restrict__ z, const float* __restrict__ featin,
    __bf16* __restrict__ xh, float* __restrict__ dout,
    const float* __restrict__ stat, const float* __restrict__ gamma,
    const float* __restrict__ beta, int isfirst, int isfinal)
{
    __shared__ float sc[64], sh[64];
    int tid = threadIdx.x;
    if (tid < 64) {
        float m = stat[tid] * (1.f / NROWS);
        float v = stat[64 + tid] * (1.f / NROWS) - m * m;
        float s = gamma[tid] * rsqrtf(v + EPSBN);
        sc[tid] = s;
        sh[tid] = beta[tid] - m * s;
    }
    __syncthreads();
    size_t base = ((((size_t)blockIdx.x << 8) | tid) << 3);
    int c0 = (int)(base & 63);
    bf16x8_t zv = *(const bf16x8_t*)(z + base);
    float xv[8];
    if (isfirst) {
        float4 xa = *(const float4*)(featin + base);
        float4 xb = *(const float4*)(featin + base + 4);
#pragma unroll
        for (int j = 0; j < 4; ++j) { xv[j] = (&xa.x)[j]; xv[4 + j] = (&xb.x)[j]; }
    } else {
        bf16x8_t xr = *(const bf16x8_t*)(xh + base);
#pragma unroll
        for (int j = 0; j < 8; ++j) xv[j] = (float)xr[j];
    }
    float o[8];
#pragma unroll
    for (int j = 0; j < 8; ++j)
        o[j] = leaky_f((float)zv[j] * sc[c0 + j] + sh[c0 + j] + xv[j]);
    if (isfinal) {
        *(float4*)(dout + base)     = make_float4(o[0], o[1], o[2], o[3]);
        *(float4*)(dout + base + 4) = make_float4(o[4], o[5], o[6], o[7]);
    } else {
        bf16x8_t h;
#pragma unroll
        for (int j = 0; j < 8; ++j) h[j] = (__bf16)o[j];
        *(bf16x8_t*)(xh + base) = h;
    }
}

// once-per-call prep: features->bf16 mirror, weights->transposed bf16, zero
// stats, premasked transposed indices cidxT[k][n] (masked-out -> NROWS;
// built thread-per-row: coalesced 9-entry reads + 9 coalesced stores),
// zero sentinel rows. Mask encoding detect: center (k=4) always True ->
// raw byte 13 nonzero iff byte-encoded; zero if int32/float32-encoded.
__global__ __launch_bounds__(256) void prep_kernel(
    const float* __restrict__ feat, const float* __restrict__ w1,
    const float* __restrict__ w2, const int* __restrict__ nidx,
    const unsigned char* __restrict__ mraw,
    __bf16* __restrict__ fh, __bf16* __restrict__ yh,
    __bf16* __restrict__ wtp, int* __restrict__ cidxT,
    float* __restrict__ stats)
{
    size_t t = ((size_t)blockIdx.x << 8) | threadIdx.x;
    if (t < 1024) stats[t] = 0.f;
    if (t < 64) {   // zero sentinel rows
        fh[(size_t)NROWS * 64 + t] = (__bf16)0.f;
        yh[(size_t)NROWS * 64 + t] = (__bf16)0.f;
    }
    if (t < 1048576) {  // features: 8 floats -> 8 bf16 per thread
        size_t i = t << 3;
        float4 a = *(const float4*)(feat + i);
        float4 b = *(const float4*)(feat + i + 4);
        bf16x8_t h;
        h[0] = (__bf16)a.x; h[1] = (__bf16)a.y; h[2] = (__bf16)a.z; h[3] = (__bf16)a.w;
        h[4] = (__bf16)b.x; h[5] = (__bf16)b.y; h[6] = (__bf16)b.z; h[7] = (__bf16)b.w;
        *(bf16x8_t*)(fh + i) = h;
    }
    if (t < 294912) {   // wtp[cv][b][k][d][c] = w[b][k][c][d]
        int o = (int)t;
        int c = o & 63, d = (o >> 6) & 63;
        int kk = o >> 12;              // 0..71
        int k = kk % 9, bb = (kk / 9) & 3, cv = kk / 36;
        const float* w = cv ? w2 : w1;
        float v = w[((size_t)((bb * 9 + k) * 64 + c) << 6) + d];
        wtp[o] = (__bf16)v;
    }
    if (t < NROWS) {    // cidxT: one thread per row n, 9 entries
        int n = (int)t;
        bool benc = (mraw[13] != 0);
        const unsigned int* mw = (const unsigned int*)mraw;
#pragma unroll
        for (int j = 0; j < 9; ++j) {
            int e = n * 9 + j;
            bool m = benc ? (mraw[e] != 0) : (mw[e] != 0u);
            cidxT[j * NROWS + n] = m ? nidx[e] : NROWS;
        }
    }
}

extern "C" void kernel_launch(void* const* d_in, const int* in_sizes, int n_in,
                              void* d_out, int out_size, void* d_ws, size_t ws_size,
                              hipStream_t stream) {
    const float* feat = (const float*)d_in[0];
    const int* nidx = (const int*)d_in[1];
    const unsigned char* mraw = (const unsigned char*)d_in[2];
    const float* w1 = (const float*)d_in[3];
    const float* g1 = (const float*)d_in[4];
    const float* b1 = (const float*)d_in[5];
    const float* w2 = (const float*)d_in[6];
    const float* g2 = (const float*)d_in[7];
    const float* b2 = (const float*)d_in[8];
    float* out = (float*)d_out;

    char* ws = (char*)d_ws;
    __bf16* xh    = (__bf16*)ws;                       // (N+1)x64 bf16 residual
    __bf16* yh    = (__bf16*)(ws + 17825792);          // (N+1)x64 bf16 conv1 out
    __bf16* zh    = (__bf16*)(ws + 35651584);          // N x64 bf16 conv2 out
    __bf16* wtp   = (__bf16*)(ws + 53477376);          // 0.59 MB transposed weights
    float*  stats = (float*)(ws + 54525952);           // 8 stages x 128 floats
    int*    cidxT = (int*)(ws + 54591488);             // 4.72 MB premasked idx^T

    prep_kernel<<<4096, 256, 0, stream>>>(feat, w1, w2, nidx, mraw,
                                          xh, yh, wtp, cidxT, stats);

    for (int b = 0; b < 4; ++b) {
        conv_kernel<<<512, 256, 0, stream>>>(
            xh, cidxT, wtp + (size_t)b * 9 * 4096,
            yh, stats + (size_t)(2 * b) * 128);
        bnact_kernel<<<4096, 256, 0, stream>>>(
            yh, stats + (size_t)(2 * b) * 128, g1 + b * 64, b1 + b * 64);
        conv_kernel<<<512, 256, 0, stream>>>(
            yh, cidxT, wtp + (size_t)(4 + b) * 9 * 4096,
            zh, stats + (size_t)(2 * b + 1) * 128);
        resid_kernel<<<4096, 256, 0, stream>>>(
            zh, feat, xh, out,
            stats + (size_t)(2 * b + 1) * 128, g2 + b * 64, b2 + b * 64,
            (b == 0) ? 1 : 0, (b == 3) ? 1 : 0);
    }
}